// Round 5
// baseline (194.921 us; speedup 1.0000x reference)
//
#include <hip/hip_runtime.h>
#include <hip/hip_fp16.h>
#include <math.h>

#define N_NODES 50000
#define IN_F 256
#define OUT_F 64
#define NBUCK 391   // ceil(50000/128): buckets of 128 destination rows
#define CHUNK 4096  // edges per bin block
#define CAPB 4608   // bucket capacity: mean 4096 + 8 sigma (sigma=64)
#define GEMM_ROWS 256
#define GEMM_BLOCKS ((N_NODES + GEMM_ROWS - 1) / GEMM_ROWS)   // 196
#define RED_BLOCKS 256

typedef unsigned int uint;
typedef __attribute__((ext_vector_type(8))) short short8v;
typedef __attribute__((ext_vector_type(4))) short short4v;
typedef __attribute__((ext_vector_type(4))) float f32x4;

// ---------------------------------------------------------------------------
// 3-launch pipeline:
//   wprep:  W fp32 -> bf16 hi/lo split, transposed [col][k]; zeroes gcnt +
//           steal queue (graph-replay safe).
//   fused:  blocks [0,G) = bin role (single-pass 391-bucket binning, int LDS
//           atomics + one global atomic base-claim per (block,bucket));
//           blocks [G,G+196) = gemm role (MFMA bf16x2 3-term split, 256
//           rows/block, 1024 thr). Independent work overlaps on the CUs.
//   reduce: persistent 256 blocks (1 per CU), dynamic bucket stealing for
//           balance. Per bucket: LDS stage + 128-row hist/scan/sort (int
//           atomics only), half-wave-per-edge register reduce, fused tanh.
// ---------------------------------------------------------------------------

__device__ __forceinline__ short bf16_trunc(float f) {
    return (short)(__float_as_uint(f) >> 16);
}
__device__ __forceinline__ float bf16_tof(short s) {
    return __uint_as_float(((uint)(unsigned short)s) << 16);
}
__device__ __forceinline__ short bf16_rne(float f) {
    uint u = __float_as_uint(f);
    uint r = u + 0x7FFF + ((u >> 16) & 1);
    return (short)(r >> 16);
}

// ---- W prep: transpose + bf16x2 split; zero bucket counters + queue ----
__global__ __launch_bounds__(256) void wprep_kernel(const float* __restrict__ W,
                                                    short* __restrict__ Whi,
                                                    short* __restrict__ Wlo,
                                                    int* __restrict__ gcnt) {
    const int t = threadIdx.x;
    const int k0 = blockIdx.x * 32;
    if (blockIdx.x == 0) {
        for (int i = t; i < NBUCK + 1; i += 256) gcnt[i] = 0;  // +1 = steal queue
    }

    __shared__ float buf[32][65];
    for (int i = t; i < 32 * 64; i += 256) {
        int kk = i >> 6, c = i & 63;
        buf[kk][c] = W[(k0 + kk) * 64 + c];   // coalesced
    }
    __syncthreads();
    {
        int c = t & 63, g = t >> 6;  // 64 cols x 4 octets of k
        short8v vh, vl;
        for (int j = 0; j < 8; ++j) {
            float f = buf[g * 8 + j][c];
            short h = bf16_trunc(f);
            vh[j] = h;
            vl[j] = bf16_rne(f - bf16_tof(h));
        }
        *(short8v*)&Whi[c * IN_F + k0 + g * 8] = vh;
        *(short8v*)&Wlo[c * IN_F + k0 + g * 8] = vl;
    }
}

// ---- fused: bin (blocks [0,G)) || gemm (blocks [G, G+GEMM_BLOCKS)) ----
__global__ __launch_bounds__(1024) void fused_kernel(const float* __restrict__ feat,
                                                     const short* __restrict__ Whi,
                                                     const short* __restrict__ Wlo,
                                                     __half* __restrict__ sup,
                                                     const int* __restrict__ erow,
                                                     const int* __restrict__ ecol,
                                                     const float* __restrict__ ew,
                                                     int* __restrict__ gcnt,
                                                     int2* __restrict__ ecw,
                                                     int E, int G) {
    __shared__ char ldsraw[51200];   // union: bin 34.4 KB | gemm 50 KB
    const int t = threadIdx.x;

    if ((int)blockIdx.x < G) {
        // ================= bin role =================
        int*   h    = (int*)ldsraw;                       // NBUCK ints
        uint*  pkst = (uint*)(ldsraw + 1600);             // 16 KB
        float* wst  = (float*)(ldsraw + 1600 + 16384);    // 16 KB
        const int base = blockIdx.x * CHUNK;

        for (int i = t; i < NBUCK; i += 1024) h[i] = 0;
        __syncthreads();

        const int e4 = base + 4 * t;
        if (e4 + 3 < E) {
            int4   r4 = *(const int4*)(erow + e4);
            int4   c4 = *(const int4*)(ecol + e4);
            float4 w4 = *(const float4*)(ew + e4);
            pkst[4 * t + 0] = ((uint)r4.x << 16) | (uint)c4.x;
            pkst[4 * t + 1] = ((uint)r4.y << 16) | (uint)c4.y;
            pkst[4 * t + 2] = ((uint)r4.z << 16) | (uint)c4.z;
            pkst[4 * t + 3] = ((uint)r4.w << 16) | (uint)c4.w;
            *(float4*)(wst + 4 * t) = w4;
            atomicAdd(&h[r4.x >> 7], 1);
            atomicAdd(&h[r4.y >> 7], 1);
            atomicAdd(&h[r4.z >> 7], 1);
            atomicAdd(&h[r4.w >> 7], 1);
        } else {
            for (int k = 0; k < 4; ++k) {
                int e = e4 + k;
                if (e < E) {
                    int row = erow[e];
                    pkst[4 * t + k] = ((uint)row << 16) | (uint)ecol[e];
                    wst[4 * t + k] = ew[e];
                    atomicAdd(&h[row >> 7], 1);
                }
            }
        }
        __syncthreads();

        // claim global base per non-empty bucket
        for (int i = t; i < NBUCK; i += 1024) {
            int c = h[i];
            if (c > 0) h[i] = atomicAdd(&gcnt[i], c);
        }
        __syncthreads();

        const int lim = min(CHUNK, E - base);
        for (int i = t; i < lim; i += 1024) {
            uint  pk = pkst[i];
            float w  = wst[i];
            int b = (int)(pk >> 23);               // row >> 7
            int pos = atomicAdd(&h[b], 1);         // absolute position in bucket
            if (pos < CAPB)
                ecw[(size_t)b * CAPB + pos] =
                    make_int2((int)(pk & 0x7FFFFF), __float_as_int(w));
        }
    } else {
        // ================= gemm role =================
        short* As_hi = (short*)ldsraw;        // 256 x 40
        short* As_lo = As_hi + 10240;
        short* Bs_hi = As_lo + 10240;         // 64 x 40
        short* Bs_lo = Bs_hi + 2560;

        const int row0 = ((int)blockIdx.x - G) * GEMM_ROWS;
        const int l = t & 63;
        const int wid = t >> 6;
        const int lr = l & 15;
        const int lk = (l >> 4) * 8;
        const int wrow = wid * 16;

        // A staging: 4 threads per row, 8 floats each
        const int ar = t >> 2, aq = t & 3;
        int gr = row0 + ar; if (gr >= N_NODES) gr = N_NODES - 1;
        const float4* asrc = (const float4*)(feat + (size_t)gr * IN_F);
        // B staging: 16 threads per col, 2 k each
        const int bc = t >> 4, bq = t & 15;
        const uint* bsrch = (const uint*)(Whi + bc * IN_F);
        const uint* bsrcl = (const uint*)(Wlo + bc * IN_F);

        f32x4 acc[4];
#pragma unroll
        for (int nn = 0; nn < 4; ++nn) acc[nn] = (f32x4)(0.f);

        float4 av0 = asrc[aq * 2];
        float4 av1 = asrc[aq * 2 + 1];
        uint bh = bsrch[bq];
        uint bl = bsrcl[bq];

        for (int ch = 0; ch < 8; ++ch) {
            {
                float fx[8] = {av0.x, av0.y, av0.z, av0.w, av1.x, av1.y, av1.z, av1.w};
                short4v h4a, l4a, h4b, l4b;
#pragma unroll
                for (int j = 0; j < 4; ++j) {
                    short hh = bf16_trunc(fx[j]);
                    h4a[j] = hh;
                    l4a[j] = bf16_rne(fx[j] - bf16_tof(hh));
                }
#pragma unroll
                for (int j = 0; j < 4; ++j) {
                    short hh = bf16_trunc(fx[4 + j]);
                    h4b[j] = hh;
                    l4b[j] = bf16_rne(fx[4 + j] - bf16_tof(hh));
                }
                *(short4v*)&As_hi[ar * 40 + aq * 8]     = h4a;
                *(short4v*)&As_hi[ar * 40 + aq * 8 + 4] = h4b;
                *(short4v*)&As_lo[ar * 40 + aq * 8]     = l4a;
                *(short4v*)&As_lo[ar * 40 + aq * 8 + 4] = l4b;
                *(uint*)&Bs_hi[bc * 40 + bq * 2] = bh;
                *(uint*)&Bs_lo[bc * 40 + bq * 2] = bl;
            }
            __syncthreads();

            if (ch < 7) {
                av0 = asrc[(ch + 1) * 8 + aq * 2];
                av1 = asrc[(ch + 1) * 8 + aq * 2 + 1];
                bh = bsrch[(ch + 1) * 16 + bq];
                bl = bsrcl[(ch + 1) * 16 + bq];
            }

            short8v ah = *(short8v*)&As_hi[(wrow + lr) * 40 + lk];
            short8v al = *(short8v*)&As_lo[(wrow + lr) * 40 + lk];
            short8v wh[4], wl[4];
#pragma unroll
            for (int nn = 0; nn < 4; ++nn) {
                wh[nn] = *(short8v*)&Bs_hi[(nn * 16 + lr) * 40 + lk];
                wl[nn] = *(short8v*)&Bs_lo[(nn * 16 + lr) * 40 + lk];
            }
#pragma unroll
            for (int nn = 0; nn < 4; ++nn) {
                acc[nn] = __builtin_amdgcn_mfma_f32_16x16x32_bf16(ah, wh[nn], acc[nn], 0, 0, 0);
                acc[nn] = __builtin_amdgcn_mfma_f32_16x16x32_bf16(ah, wl[nn], acc[nn], 0, 0, 0);
                acc[nn] = __builtin_amdgcn_mfma_f32_16x16x32_bf16(al, wh[nn], acc[nn], 0, 0, 0);
            }
            __syncthreads();
        }

        // epilogue: transpose via LDS (overlays staging), coalesced store
        short* sup_s = (short*)ldsraw;  // 256 x 64 halves = 32 KB
#pragma unroll
        for (int nn = 0; nn < 4; ++nn) {
            int cc = nn * 16 + lr;
            int rr = wrow + (l >> 4) * 4;
#pragma unroll
            for (int j = 0; j < 4; ++j) {
                __half hv = __float2half(acc[nn][j]);
                sup_s[(rr + j) * 64 + cc] = *(short*)&hv;
            }
        }
        __syncthreads();
        {
            int r = t >> 2;
            int grow = row0 + r;
            if (grow < N_NODES) {
                const uint4* s4 = (const uint4*)&sup_s[r * 64 + (t & 3) * 16];
                uint4* d4 = (uint4*)(sup + (size_t)grow * OUT_F + (t & 3) * 16);
                d4[0] = s4[0];
                d4[1] = s4[1];
            }
        }
    }
}

// ---- persistent bucket reduce: LDS sort + register accumulate, stealing ----
__global__ __launch_bounds__(1024) void reduce_kernel(const __half* __restrict__ sup,
                                                      const int* __restrict__ gcnt,
                                                      const int2* __restrict__ ecw,
                                                      const int* __restrict__ active,
                                                      float* __restrict__ out,
                                                      int* __restrict__ nextq) {
    __shared__ int2 stA[CAPB];   // raw bucket edges      36.9 KB
    __shared__ int2 stB[CAPB];   // row-sorted edges      36.9 KB
    __shared__ int h[128];
    __shared__ int sc[128];
    __shared__ int cur[128];
    __shared__ int bshare;
    const int t = threadIdx.x;
    const int act = *active;

    const int wid  = t >> 6;
    const int lane = t & 63;
    const int hl   = lane & 31;
    const bool hi  = lane >= 32;

    int b = blockIdx.x;
    while (b < NBUCK) {
        int n = gcnt[b]; if (n > CAPB) n = CAPB;
        const int2* eptr = ecw + (size_t)b * CAPB;

        if (t < 128) h[t] = 0;
        __syncthreads();

        // stage + 128-row histogram (native ds_add_u32)
        for (int i = t; i < n; i += 1024) {
            int2 d = eptr[i];
            stA[i] = d;
            atomicAdd(&h[(d.x >> 16) & 127], 1);
        }
        __syncthreads();

        // 128-entry inclusive scan
        if (t < 128) sc[t] = h[t];
        __syncthreads();
        for (int off = 1; off < 128; off <<= 1) {
            int u = (t < 128 && t >= off) ? sc[t - off] : 0;
            __syncthreads();
            if (t < 128) sc[t] += u;
            __syncthreads();
        }
        if (t < 128) cur[t] = sc[t] - h[t];
        __syncthreads();

        // scatter to row-sorted order within LDS
        for (int i = t; i < n; i += 1024) {
            int2 d = stA[i];
            int r = (d.x >> 16) & 127;
            int pos = atomicAdd(&cur[r], 1);
            stB[pos] = make_int2(d.x & 0xFFFF, d.y);
        }
        __syncthreads();

        // per-row register reduce: one wave per row, half-wave per edge
        for (int r = wid; r < 128; r += 16) {
            int row = b * 128 + r;
            if (row >= N_NODES) break;   // wave-uniform (last bucket only)
            const int s = sc[r] - h[r];
            const int e = sc[r];
            float ax = 0.f, ay = 0.f;
            int j = s;
            for (; j + 8 <= e; j += 8) {
#pragma unroll
                for (int q = 0; q < 4; ++q) {
                    int2 pa = stB[j + 2 * q];
                    int2 pb = stB[j + 2 * q + 1];
                    int   col = hi ? pb.x : pa.x;
                    float w   = __int_as_float(hi ? pb.y : pa.y);
                    const __half2* hp = (const __half2*)(sup + ((size_t)col << 6));
                    float2 v = __half22float2(hp[hl]);
                    ax += w * v.x;
                    ay += w * v.y;
                }
            }
            for (; j + 2 <= e; j += 2) {
                int2 pa = stB[j];
                int2 pb = stB[j + 1];
                int   col = hi ? pb.x : pa.x;
                float w   = __int_as_float(hi ? pb.y : pa.y);
                const __half2* hp = (const __half2*)(sup + ((size_t)col << 6));
                float2 v = __half22float2(hp[hl]);
                ax += w * v.x;
                ay += w * v.y;
            }
            if (j < e) {  // odd tail: hi half contributes zero
                int2 pa = stB[j];
                int   col = pa.x;
                float w   = hi ? 0.f : __int_as_float(pa.y);
                const __half2* hp = (const __half2*)(sup + ((size_t)col << 6));
                float2 v = __half22float2(hp[hl]);
                ax += w * v.x;
                ay += w * v.y;
            }

            ax += __shfl_xor(ax, 32, 64);
            ay += __shfl_xor(ay, 32, 64);

            if (!hi) {
                if (act) { ax = tanhf(ax); ay = tanhf(ay); }
                *(float2*)&out[((size_t)row << 6) + 2 * hl] = make_float2(ax, ay);
            }
        }

        __syncthreads();   // all reads of h/sc done before next bucket reuses
        if (t == 0) bshare = RED_BLOCKS + atomicAdd(nextq, 1);
        __syncthreads();
        b = bshare;
    }
}

extern "C" void kernel_launch(void* const* d_in, const int* in_sizes, int n_in,
                              void* d_out, int out_size, void* d_ws, size_t ws_size,
                              hipStream_t stream) {
    const float* feat = (const float*)d_in[0];
    const float* W    = (const float*)d_in[1];
    const int*   erow = (const int*)d_in[2];
    const int*   ecol = (const int*)d_in[3];
    const float* ew   = (const float*)d_in[4];
    const int*   act  = (const int*)d_in[5];
    float* out = (float*)d_out;

    const int E = in_sizes[2];
    const int G = (E + CHUNK - 1) / CHUNK;

    // workspace carve-up (16B-aligned segments)
    char* ws = (char*)d_ws;
    __half* sup  = (__half*)ws; ws += (size_t)N_NODES * OUT_F * 2;         // 6.4 MB
    int2*   ecw  = (int2*)ws;   ws += (size_t)NBUCK * CAPB * 8;            // 14.4 MB
    int*    gcnt = (int*)ws;    ws += ((size_t)(NBUCK + 1) * 4 + 15) & ~15;
    short*  Whi  = (short*)ws;  ws += (size_t)OUT_F * IN_F * 2;            // 32 KB
    short*  Wlo  = (short*)ws;  ws += (size_t)OUT_F * IN_F * 2;            // 32 KB
    int*    nextq = gcnt + NBUCK;   // steal queue (zeroed by wprep)

    wprep_kernel<<<8, 256, 0, stream>>>(W, Whi, Wlo, gcnt);
    fused_kernel<<<G + GEMM_BLOCKS, 1024, 0, stream>>>(feat, Whi, Wlo, sup,
                                                       erow, ecol, ew, gcnt, ecw, E, G);
    reduce_kernel<<<RED_BLOCKS, 1024, 0, stream>>>(sup, gcnt, ecw, act, out, nextq);
}

// Round 7
// 188.858 us; speedup vs baseline: 1.0321x; 1.0321x over previous
//
#include <hip/hip_runtime.h>
#include <hip/hip_fp16.h>
#include <math.h>

#define N_NODES 50000
#define IN_F 256
#define OUT_F 64
#define NBUCK 391   // ceil(50000/128): buckets of 128 destination rows
#define CHUNK 4096  // edges per bin block
#define CAPB 4608   // bucket capacity: mean 4096 + 8 sigma (sigma=64)

typedef unsigned int uint;
typedef __attribute__((ext_vector_type(8))) short short8v;
typedef __attribute__((ext_vector_type(4))) short short4v;
typedef __attribute__((ext_vector_type(4))) float f32x4;

// ---------------------------------------------------------------------------
// 4-kernel pipeline (round-6 = round-4 wprep/gemm/bin + high-occupancy reduce):
//   wprep:  W fp32 -> bf16 hi/lo split, transposed [col][k]; zeroes gcnt.
//   gemm:   support = feat @ W via MFMA bf16x2 3-term split, stored FP16.
//   bin:    single-pass 391-bucket binning (int LDS atomics + one global
//           atomic base-claim per (block,bucket)), packed (row7|col16, w).
//   reduce: one block per 128-row bucket, 512 thr, 37.5 KB LDS -> 4 blocks/CU
//           => all 391 blocks co-resident (no scheduling tail). No stA: hist
//           reads row words from global, sort re-reads ecw (L2-hot) into stB.
//           Then half-wave-per-edge register reduce, fused tanh.
// ---------------------------------------------------------------------------

__device__ __forceinline__ short bf16_trunc(float f) {
    return (short)(__float_as_uint(f) >> 16);
}
__device__ __forceinline__ float bf16_tof(short s) {
    return __uint_as_float(((uint)(unsigned short)s) << 16);
}
__device__ __forceinline__ short bf16_rne(float f) {
    uint u = __float_as_uint(f);
    uint r = u + 0x7FFF + ((u >> 16) & 1);
    return (short)(r >> 16);
}

// ---- W prep: transpose + bf16x2 split; zero bucket counters ----
__global__ __launch_bounds__(256) void wprep_kernel(const float* __restrict__ W,
                                                    short* __restrict__ Whi,
                                                    short* __restrict__ Wlo,
                                                    int* __restrict__ gcnt) {
    const int t = threadIdx.x;
    const int k0 = blockIdx.x * 32;
    if (blockIdx.x == 0) {
        for (int i = t; i < NBUCK; i += 256) gcnt[i] = 0;
    }

    __shared__ float buf[32][65];
    for (int i = t; i < 32 * 64; i += 256) {
        int kk = i >> 6, c = i & 63;
        buf[kk][c] = W[(k0 + kk) * 64 + c];   // coalesced
    }
    __syncthreads();
    {
        int c = t & 63, g = t >> 6;  // 64 cols x 4 octets of k
        short8v vh, vl;
        for (int j = 0; j < 8; ++j) {
            float f = buf[g * 8 + j][c];
            short h = bf16_trunc(f);
            vh[j] = h;
            vl[j] = bf16_rne(f - bf16_tof(h));
        }
        *(short8v*)&Whi[c * IN_F + k0 + g * 8] = vh;
        *(short8v*)&Wlo[c * IN_F + k0 + g * 8] = vl;
    }
}

// ---- MFMA bf16x2 projection: support(FP16) = feat @ W ----
// block: 256 thr (4 waves), 128 rows x 64 cols; wave: 32 rows (M_rep=2, N_rep=4)
__global__ __launch_bounds__(256) void gemm_kernel(const float* __restrict__ feat,
                                                   const short* __restrict__ Whi,
                                                   const short* __restrict__ Wlo,
                                                   __half* __restrict__ sup) {
    __shared__ short lds[15360];          // 30 KB
    short* As_hi = lds;                   // 128 x 40 halves (80B stride)
    short* As_lo = lds + 5120;
    short* Bs_hi = lds + 10240;           // 64 x 40 halves
    short* Bs_lo = lds + 12800;

    const int t = threadIdx.x;
    const int row0 = blockIdx.x * 128;
    const int l = t & 63;
    const int lr = l & 15;
    const int lk = (l >> 4) * 8;
    const int wrow = (t >> 6) * 32;

    // A staging ids: 2 threads per row, 16 floats each
    const int ar = t >> 1, aq = t & 1;
    int gr = row0 + ar; if (gr >= N_NODES) gr = N_NODES - 1;
    const float4* asrc = (const float4*)(feat + (size_t)gr * IN_F);
    // B staging ids: 4 threads per col, 8 k each
    const int bc = t >> 2, bp = t & 3;

    f32x4 acc[2][4];
#pragma unroll
    for (int m = 0; m < 2; ++m)
#pragma unroll
        for (int nn = 0; nn < 4; ++nn) acc[m][nn] = (f32x4)(0.f);

    for (int ch = 0; ch < 8; ++ch) {
        // prefetch chunk into regs
        float4 av[4];
#pragma unroll
        for (int i = 0; i < 4; ++i) av[i] = asrc[ch * 8 + aq * 4 + i];
        short8v bh = *(const short8v*)(Whi + bc * IN_F + ch * 32 + bp * 8);
        short8v bl = *(const short8v*)(Wlo + bc * IN_F + ch * 32 + bp * 8);

        __syncthreads();   // prior chunk's readers done
#pragma unroll
        for (int i = 0; i < 4; ++i) {
            float fx[4] = {av[i].x, av[i].y, av[i].z, av[i].w};
            short4v h4, l4;
#pragma unroll
            for (int j = 0; j < 4; ++j) {
                short h = bf16_trunc(fx[j]);
                h4[j] = h;
                l4[j] = bf16_rne(fx[j] - bf16_tof(h));
            }
            *(short4v*)&As_hi[ar * 40 + aq * 16 + i * 4] = h4;
            *(short4v*)&As_lo[ar * 40 + aq * 16 + i * 4] = l4;
        }
        *(short8v*)&Bs_hi[bc * 40 + bp * 8] = bh;
        *(short8v*)&Bs_lo[bc * 40 + bp * 8] = bl;
        __syncthreads();

        short8v ah[2], al[2], wh[4], wl[4];
#pragma unroll
        for (int m = 0; m < 2; ++m) {
            ah[m] = *(short8v*)&As_hi[(wrow + m * 16 + lr) * 40 + lk];
            al[m] = *(short8v*)&As_lo[(wrow + m * 16 + lr) * 40 + lk];
        }
#pragma unroll
        for (int nn = 0; nn < 4; ++nn) {
            wh[nn] = *(short8v*)&Bs_hi[(nn * 16 + lr) * 40 + lk];
            wl[nn] = *(short8v*)&Bs_lo[(nn * 16 + lr) * 40 + lk];
        }
#pragma unroll
        for (int m = 0; m < 2; ++m)
#pragma unroll
            for (int nn = 0; nn < 4; ++nn) {
                acc[m][nn] = __builtin_amdgcn_mfma_f32_16x16x32_bf16(ah[m], wh[nn], acc[m][nn], 0, 0, 0);
                acc[m][nn] = __builtin_amdgcn_mfma_f32_16x16x32_bf16(ah[m], wl[nn], acc[m][nn], 0, 0, 0);
                acc[m][nn] = __builtin_amdgcn_mfma_f32_16x16x32_bf16(al[m], wh[nn], acc[m][nn], 0, 0, 0);
            }
    }

    // epilogue: transpose via LDS (overlays staging buffers), coalesced store
    __syncthreads();
    short* sup_s = lds;  // 128 x 64 halves = 16 KB
#pragma unroll
    for (int m = 0; m < 2; ++m) {
        int rr = wrow + m * 16 + (l >> 4) * 4;
#pragma unroll
        for (int nn = 0; nn < 4; ++nn) {
            int cc = nn * 16 + lr;
#pragma unroll
            for (int j = 0; j < 4; ++j) {
                __half h = __float2half(acc[m][nn][j]);
                sup_s[(rr + j) * 64 + cc] = *(short*)&h;
            }
        }
    }
    __syncthreads();
    {
        int r = t >> 1, sg = (t & 1) * 32;
        int grow = row0 + r;
        if (grow < N_NODES) {
            const uint4* s4 = (const uint4*)&sup_s[r * 64 + sg];
            uint4* d4 = (uint4*)(sup + (size_t)grow * OUT_F + sg);
            d4[0] = s4[0];
            d4[1] = s4[1];
            d4[2] = s4[2];
            d4[3] = s4[3];
        }
    }
}

// ---- single-pass bucket binning (int LDS atomics only) ----
__global__ __launch_bounds__(1024) void bin_kernel(const int* __restrict__ erow,
                                                   const int* __restrict__ ecol,
                                                   const float* __restrict__ ew,
                                                   int* __restrict__ gcnt,
                                                   int2* __restrict__ ecw, int E) {
    __shared__ int   h[NBUCK];      // hist -> absolute cursor
    __shared__ uint  pkst[CHUNK];   // (row<<16)|col   16 KB
    __shared__ float wst[CHUNK];    // edge weight     16 KB
    const int t = threadIdx.x;
    const int base = blockIdx.x * CHUNK;

    for (int i = t; i < NBUCK; i += 1024) h[i] = 0;
    __syncthreads();

    const int e4 = base + 4 * t;
    if (e4 + 3 < E) {
        int4   r4 = *(const int4*)(erow + e4);
        int4   c4 = *(const int4*)(ecol + e4);
        float4 w4 = *(const float4*)(ew + e4);
        pkst[4 * t + 0] = ((uint)r4.x << 16) | (uint)c4.x;
        pkst[4 * t + 1] = ((uint)r4.y << 16) | (uint)c4.y;
        pkst[4 * t + 2] = ((uint)r4.z << 16) | (uint)c4.z;
        pkst[4 * t + 3] = ((uint)r4.w << 16) | (uint)c4.w;
        *(float4*)(wst + 4 * t) = w4;
        atomicAdd(&h[r4.x >> 7], 1);
        atomicAdd(&h[r4.y >> 7], 1);
        atomicAdd(&h[r4.z >> 7], 1);
        atomicAdd(&h[r4.w >> 7], 1);
    } else {
        for (int k = 0; k < 4; ++k) {
            int e = e4 + k;
            if (e < E) {
                int row = erow[e];
                pkst[4 * t + k] = ((uint)row << 16) | (uint)ecol[e];
                wst[4 * t + k] = ew[e];
                atomicAdd(&h[row >> 7], 1);
            }
        }
    }
    __syncthreads();

    // claim global base per non-empty bucket
    for (int i = t; i < NBUCK; i += 1024) {
        int c = h[i];
        if (c > 0) h[i] = atomicAdd(&gcnt[i], c);
    }
    __syncthreads();

    const int lim = min(CHUNK, E - base);
    for (int i = t; i < lim; i += 1024) {
        uint  pk = pkst[i];
        float w  = wst[i];
        int b = (int)(pk >> 23);               // row >> 7
        int pos = atomicAdd(&h[b], 1);         // absolute position in bucket
        if (pos < CAPB)
            ecw[(size_t)b * CAPB + pos] =
                make_int2((int)(pk & 0x7FFFFF), __float_as_int(w));
    }
}

// ---- bucket reduce: 512 thr, 37.5 KB LDS (4 blocks/CU, grid co-resident) ----
__global__ __launch_bounds__(512) void reduce_kernel(const __half* __restrict__ sup,
                                                     const int* __restrict__ gcnt,
                                                     const int2* __restrict__ ecw,
                                                     const int* __restrict__ active,
                                                     float* __restrict__ out) {
    __shared__ int2 stB[CAPB];   // row-sorted edges      36.9 KB
    __shared__ int h[128];
    __shared__ int sc[128];
    __shared__ int cur[128];
    const int t = threadIdx.x;
    const int b = blockIdx.x;

    int n = gcnt[b]; if (n > CAPB) n = CAPB;
    const int2* eptr = ecw + (size_t)b * CAPB;

    if (t < 128) h[t] = 0;
    __syncthreads();

    // phase 1: 128-row histogram from global row words (native ds_add_u32)
    for (int i = t; i < n; i += 512) {
        int x = ((const int*)eptr)[2 * i];
        atomicAdd(&h[(x >> 16) & 127], 1);
    }
    __syncthreads();

    // 128-entry inclusive scan
    if (t < 128) sc[t] = h[t];
    __syncthreads();
    for (int off = 1; off < 128; off <<= 1) {
        int u = (t < 128 && t >= off) ? sc[t - off] : 0;
        __syncthreads();
        if (t < 128) sc[t] += u;
        __syncthreads();
    }
    if (t < 128) cur[t] = sc[t] - h[t];
    __syncthreads();

    // phase 2: re-read ecw (L2-hot) and scatter row-sorted into stB
    for (int i = t; i < n; i += 512) {
        int2 d = eptr[i];
        int r = (d.x >> 16) & 127;
        int pos = atomicAdd(&cur[r], 1);
        stB[pos] = make_int2(d.x & 0xFFFF, d.y);
    }
    __syncthreads();

    // per-row register reduce: one wave per row (16 rows/wave), half-wave per
    // edge, each lane gathers a half2 (2 cols) from sup, shfl_xor(32) combine.
    const int wid  = t >> 6;
    const int lane = t & 63;
    const int hl   = lane & 31;
    const bool hi  = lane >= 32;
    const int act  = *active;

    for (int r = wid; r < 128; r += 8) {
        int row = b * 128 + r;
        if (row >= N_NODES) break;   // wave-uniform (last bucket tail only)
        const int s = sc[r] - h[r];
        const int e = sc[r];
        float ax = 0.f, ay = 0.f;
        int j = s;
        for (; j + 8 <= e; j += 8) {
#pragma unroll
            for (int q = 0; q < 4; ++q) {
                int2 pa = stB[j + 2 * q];
                int2 pb = stB[j + 2 * q + 1];
                int   col = hi ? pb.x : pa.x;
                float w   = __int_as_float(hi ? pb.y : pa.y);
                const __half2* hp = (const __half2*)(sup + ((size_t)col << 6));
                float2 v = __half22float2(hp[hl]);
                ax += w * v.x;
                ay += w * v.y;
            }
        }
        for (; j + 2 <= e; j += 2) {
            int2 pa = stB[j];
            int2 pb = stB[j + 1];
            int   col = hi ? pb.x : pa.x;
            float w   = __int_as_float(hi ? pb.y : pa.y);
            const __half2* hp = (const __half2*)(sup + ((size_t)col << 6));
            float2 v = __half22float2(hp[hl]);
            ax += w * v.x;
            ay += w * v.y;
        }
        if (j < e) {  // odd tail: hi half contributes zero
            int2 pa = stB[j];
            int   col = pa.x;
            float w   = hi ? 0.f : __int_as_float(pa.y);
            const __half2* hp = (const __half2*)(sup + ((size_t)col << 6));
            float2 v = __half22float2(hp[hl]);
            ax += w * v.x;
            ay += w * v.y;
        }

        ax += __shfl_xor(ax, 32, 64);
        ay += __shfl_xor(ay, 32, 64);

        if (!hi) {
            if (act) { ax = tanhf(ax); ay = tanhf(ay); }
            *(float2*)&out[((size_t)row << 6) + 2 * hl] = make_float2(ax, ay);
        }
    }
}

extern "C" void kernel_launch(void* const* d_in, const int* in_sizes, int n_in,
                              void* d_out, int out_size, void* d_ws, size_t ws_size,
                              hipStream_t stream) {
    const float* feat = (const float*)d_in[0];
    const float* W    = (const float*)d_in[1];
    const int*   erow = (const int*)d_in[2];
    const int*   ecol = (const int*)d_in[3];
    const float* ew   = (const float*)d_in[4];
    const int*   act  = (const int*)d_in[5];
    float* out = (float*)d_out;

    const int E = in_sizes[2];
    const int G = (E + CHUNK - 1) / CHUNK;

    // workspace carve-up (16B-aligned segments)
    char* ws = (char*)d_ws;
    __half* sup  = (__half*)ws; ws += (size_t)N_NODES * OUT_F * 2;     // 6.4 MB
    int2*   ecw  = (int2*)ws;   ws += (size_t)NBUCK * CAPB * 8;        // 14.4 MB
    int*    gcnt = (int*)ws;    ws += ((size_t)NBUCK * 4 + 15) & ~15;  // 1.6 KB
    short*  Whi  = (short*)ws;  ws += (size_t)OUT_F * IN_F * 2;        // 32 KB
    short*  Wlo  = (short*)ws;  ws += (size_t)OUT_F * IN_F * 2;        // 32 KB

    wprep_kernel<<<8, 256, 0, stream>>>(W, Whi, Wlo, gcnt);
    gemm_kernel<<<(N_NODES + 127) / 128, 256, 0, stream>>>(feat, Whi, Wlo, sup);
    bin_kernel<<<G, 1024, 0, stream>>>(erow, ecol, ew, gcnt, ecw, E);
    reduce_kernel<<<NBUCK, 512, 0, stream>>>(sup, gcnt, ecw, act, out);
}

// Round 8
// 173.438 us; speedup vs baseline: 1.1239x; 1.0889x over previous
//
#include <hip/hip_runtime.h>
#include <hip/hip_fp16.h>
#include <math.h>

#define N_NODES 50000
#define IN_F 256
#define OUT_F 64
#define NBUCK 391   // ceil(50000/128): buckets of 128 destination rows
#define CHUNK 4096  // edges per bin block
#define CAPB 4608   // bucket capacity: mean 4096 + 8 sigma (sigma=64)

typedef unsigned int uint;
typedef __attribute__((ext_vector_type(8))) short short8v;
typedef __attribute__((ext_vector_type(4))) short short4v;
typedef __attribute__((ext_vector_type(4))) float f32x4;

// ---------------------------------------------------------------------------
// 4-kernel pipeline (round-8 = round-4 wprep/gemm/bin/reduce-sort + NEW
// quarter-wave-per-edge gather):
//   wprep:  W fp32 -> bf16 hi/lo split, transposed [col][k]; zeroes gcnt.
//   gemm:   support = feat @ W via MFMA bf16x2 3-term split, stored FP16.
//   bin:    single-pass 391-bucket binning (int LDS atomics + one global
//           atomic base-claim per (block,bucket)), packed (row7|col16, w).
//   reduce: one block per 128-row bucket, 1024 thr, 75 KB LDS (2 blocks/CU
//           co-resident): LDS stage + 128-row hist/scan/sort (int atomics),
//           then QUARTER-WAVE-per-edge gather: lane-group qg owns edge j+qg
//           (per-lane stB read, 4x fewer LDS ops), sublane sl gathers half4
//           of the sup row; shfl_xor(16,32) combine; fused tanh, float4 store.
// ---------------------------------------------------------------------------

__device__ __forceinline__ short bf16_trunc(float f) {
    return (short)(__float_as_uint(f) >> 16);
}
__device__ __forceinline__ float bf16_tof(short s) {
    return __uint_as_float(((uint)(unsigned short)s) << 16);
}
__device__ __forceinline__ short bf16_rne(float f) {
    uint u = __float_as_uint(f);
    uint r = u + 0x7FFF + ((u >> 16) & 1);
    return (short)(r >> 16);
}

// ---- W prep: transpose + bf16x2 split; zero bucket counters ----
__global__ __launch_bounds__(256) void wprep_kernel(const float* __restrict__ W,
                                                    short* __restrict__ Whi,
                                                    short* __restrict__ Wlo,
                                                    int* __restrict__ gcnt) {
    const int t = threadIdx.x;
    const int k0 = blockIdx.x * 32;
    if (blockIdx.x == 0) {
        for (int i = t; i < NBUCK; i += 256) gcnt[i] = 0;
    }

    __shared__ float buf[32][65];
    for (int i = t; i < 32 * 64; i += 256) {
        int kk = i >> 6, c = i & 63;
        buf[kk][c] = W[(k0 + kk) * 64 + c];   // coalesced
    }
    __syncthreads();
    {
        int c = t & 63, g = t >> 6;  // 64 cols x 4 octets of k
        short8v vh, vl;
        for (int j = 0; j < 8; ++j) {
            float f = buf[g * 8 + j][c];
            short h = bf16_trunc(f);
            vh[j] = h;
            vl[j] = bf16_rne(f - bf16_tof(h));
        }
        *(short8v*)&Whi[c * IN_F + k0 + g * 8] = vh;
        *(short8v*)&Wlo[c * IN_F + k0 + g * 8] = vl;
    }
}

// ---- MFMA bf16x2 projection: support(FP16) = feat @ W ----
// block: 256 thr (4 waves), 128 rows x 64 cols; wave: 32 rows (M_rep=2, N_rep=4)
__global__ __launch_bounds__(256) void gemm_kernel(const float* __restrict__ feat,
                                                   const short* __restrict__ Whi,
                                                   const short* __restrict__ Wlo,
                                                   __half* __restrict__ sup) {
    __shared__ short lds[15360];          // 30 KB
    short* As_hi = lds;                   // 128 x 40 halves (80B stride)
    short* As_lo = lds + 5120;
    short* Bs_hi = lds + 10240;           // 64 x 40 halves
    short* Bs_lo = lds + 12800;

    const int t = threadIdx.x;
    const int row0 = blockIdx.x * 128;
    const int l = t & 63;
    const int lr = l & 15;
    const int lk = (l >> 4) * 8;
    const int wrow = (t >> 6) * 32;

    // A staging ids: 2 threads per row, 16 floats each
    const int ar = t >> 1, aq = t & 1;
    int gr = row0 + ar; if (gr >= N_NODES) gr = N_NODES - 1;
    const float4* asrc = (const float4*)(feat + (size_t)gr * IN_F);
    // B staging ids: 4 threads per col, 8 k each
    const int bc = t >> 2, bp = t & 3;

    f32x4 acc[2][4];
#pragma unroll
    for (int m = 0; m < 2; ++m)
#pragma unroll
        for (int nn = 0; nn < 4; ++nn) acc[m][nn] = (f32x4)(0.f);

    for (int ch = 0; ch < 8; ++ch) {
        // prefetch chunk into regs
        float4 av[4];
#pragma unroll
        for (int i = 0; i < 4; ++i) av[i] = asrc[ch * 8 + aq * 4 + i];
        short8v bh = *(const short8v*)(Whi + bc * IN_F + ch * 32 + bp * 8);
        short8v bl = *(const short8v*)(Wlo + bc * IN_F + ch * 32 + bp * 8);

        __syncthreads();   // prior chunk's readers done
#pragma unroll
        for (int i = 0; i < 4; ++i) {
            float fx[4] = {av[i].x, av[i].y, av[i].z, av[i].w};
            short4v h4, l4;
#pragma unroll
            for (int j = 0; j < 4; ++j) {
                short h = bf16_trunc(fx[j]);
                h4[j] = h;
                l4[j] = bf16_rne(fx[j] - bf16_tof(h));
            }
            *(short4v*)&As_hi[ar * 40 + aq * 16 + i * 4] = h4;
            *(short4v*)&As_lo[ar * 40 + aq * 16 + i * 4] = l4;
        }
        *(short8v*)&Bs_hi[bc * 40 + bp * 8] = bh;
        *(short8v*)&Bs_lo[bc * 40 + bp * 8] = bl;
        __syncthreads();

        short8v ah[2], al[2], wh[4], wl[4];
#pragma unroll
        for (int m = 0; m < 2; ++m) {
            ah[m] = *(short8v*)&As_hi[(wrow + m * 16 + lr) * 40 + lk];
            al[m] = *(short8v*)&As_lo[(wrow + m * 16 + lr) * 40 + lk];
        }
#pragma unroll
        for (int nn = 0; nn < 4; ++nn) {
            wh[nn] = *(short8v*)&Bs_hi[(nn * 16 + lr) * 40 + lk];
            wl[nn] = *(short8v*)&Bs_lo[(nn * 16 + lr) * 40 + lk];
        }
#pragma unroll
        for (int m = 0; m < 2; ++m)
#pragma unroll
            for (int nn = 0; nn < 4; ++nn) {
                acc[m][nn] = __builtin_amdgcn_mfma_f32_16x16x32_bf16(ah[m], wh[nn], acc[m][nn], 0, 0, 0);
                acc[m][nn] = __builtin_amdgcn_mfma_f32_16x16x32_bf16(ah[m], wl[nn], acc[m][nn], 0, 0, 0);
                acc[m][nn] = __builtin_amdgcn_mfma_f32_16x16x32_bf16(al[m], wh[nn], acc[m][nn], 0, 0, 0);
            }
    }

    // epilogue: transpose via LDS (overlays staging buffers), coalesced store
    __syncthreads();
    short* sup_s = lds;  // 128 x 64 halves = 16 KB
#pragma unroll
    for (int m = 0; m < 2; ++m) {
        int rr = wrow + m * 16 + (l >> 4) * 4;
#pragma unroll
        for (int nn = 0; nn < 4; ++nn) {
            int cc = nn * 16 + lr;
#pragma unroll
            for (int j = 0; j < 4; ++j) {
                __half h = __float2half(acc[m][nn][j]);
                sup_s[(rr + j) * 64 + cc] = *(short*)&h;
            }
        }
    }
    __syncthreads();
    {
        int r = t >> 1, sg = (t & 1) * 32;
        int grow = row0 + r;
        if (grow < N_NODES) {
            const uint4* s4 = (const uint4*)&sup_s[r * 64 + sg];
            uint4* d4 = (uint4*)(sup + (size_t)grow * OUT_F + sg);
            d4[0] = s4[0];
            d4[1] = s4[1];
            d4[2] = s4[2];
            d4[3] = s4[3];
        }
    }
}

// ---- single-pass bucket binning (int LDS atomics only) ----
__global__ __launch_bounds__(1024) void bin_kernel(const int* __restrict__ erow,
                                                   const int* __restrict__ ecol,
                                                   const float* __restrict__ ew,
                                                   int* __restrict__ gcnt,
                                                   int2* __restrict__ ecw, int E) {
    __shared__ int   h[NBUCK];      // hist -> absolute cursor
    __shared__ uint  pkst[CHUNK];   // (row<<16)|col   16 KB
    __shared__ float wst[CHUNK];    // edge weight     16 KB
    const int t = threadIdx.x;
    const int base = blockIdx.x * CHUNK;

    for (int i = t; i < NBUCK; i += 1024) h[i] = 0;
    __syncthreads();

    const int e4 = base + 4 * t;
    if (e4 + 3 < E) {
        int4   r4 = *(const int4*)(erow + e4);
        int4   c4 = *(const int4*)(ecol + e4);
        float4 w4 = *(const float4*)(ew + e4);
        pkst[4 * t + 0] = ((uint)r4.x << 16) | (uint)c4.x;
        pkst[4 * t + 1] = ((uint)r4.y << 16) | (uint)c4.y;
        pkst[4 * t + 2] = ((uint)r4.z << 16) | (uint)c4.z;
        pkst[4 * t + 3] = ((uint)r4.w << 16) | (uint)c4.w;
        *(float4*)(wst + 4 * t) = w4;
        atomicAdd(&h[r4.x >> 7], 1);
        atomicAdd(&h[r4.y >> 7], 1);
        atomicAdd(&h[r4.z >> 7], 1);
        atomicAdd(&h[r4.w >> 7], 1);
    } else {
        for (int k = 0; k < 4; ++k) {
            int e = e4 + k;
            if (e < E) {
                int row = erow[e];
                pkst[4 * t + k] = ((uint)row << 16) | (uint)ecol[e];
                wst[4 * t + k] = ew[e];
                atomicAdd(&h[row >> 7], 1);
            }
        }
    }
    __syncthreads();

    // claim global base per non-empty bucket
    for (int i = t; i < NBUCK; i += 1024) {
        int c = h[i];
        if (c > 0) h[i] = atomicAdd(&gcnt[i], c);
    }
    __syncthreads();

    const int lim = min(CHUNK, E - base);
    for (int i = t; i < lim; i += 1024) {
        uint  pk = pkst[i];
        float w  = wst[i];
        int b = (int)(pk >> 23);               // row >> 7
        int pos = atomicAdd(&h[b], 1);         // absolute position in bucket
        if (pos < CAPB)
            ecw[(size_t)b * CAPB + pos] =
                make_int2((int)(pk & 0x7FFFFF), __float_as_int(w));
    }
}

// ---- bucket reduce: LDS sort + quarter-wave-per-edge gather ----
__global__ __launch_bounds__(1024) void reduce_kernel(const __half* __restrict__ sup,
                                                      const int* __restrict__ gcnt,
                                                      const int2* __restrict__ ecw,
                                                      const int* __restrict__ active,
                                                      float* __restrict__ out) {
    __shared__ int2 stA[CAPB];   // raw bucket edges      36.9 KB
    __shared__ int2 stB[CAPB];   // row-sorted edges      36.9 KB
    __shared__ int h[128];
    __shared__ int sc[128];
    __shared__ int cur[128];
    const int t = threadIdx.x;
    const int b = blockIdx.x;

    int n = gcnt[b]; if (n > CAPB) n = CAPB;
    const int2* eptr = ecw + (size_t)b * CAPB;

    if (t < 128) h[t] = 0;
    __syncthreads();

    // stage + 128-row histogram (native ds_add_u32)
    for (int i = t; i < n; i += 1024) {
        int2 d = eptr[i];
        stA[i] = d;
        atomicAdd(&h[(d.x >> 16) & 127], 1);
    }
    __syncthreads();

    // 128-entry inclusive scan
    if (t < 128) sc[t] = h[t];
    __syncthreads();
    for (int off = 1; off < 128; off <<= 1) {
        int u = (t < 128 && t >= off) ? sc[t - off] : 0;
        __syncthreads();
        if (t < 128) sc[t] += u;
        __syncthreads();
    }
    if (t < 128) cur[t] = sc[t] - h[t];
    __syncthreads();

    // scatter to row-sorted order within LDS
    for (int i = t; i < n; i += 1024) {
        int2 d = stA[i];
        int r = (d.x >> 16) & 127;
        int pos = atomicAdd(&cur[r], 1);
        stB[pos] = make_int2(d.x & 0xFFFF, d.y);
    }
    __syncthreads();

    // quarter-wave-per-edge gather: one wave per row (8 rows/wave).
    // lane group qg = lane>>4 owns edge j+qg (per-lane stB read, 32B/group
    // contiguous -> conflict-free); sublane sl = lane&15 gathers half4
    // (8B) of the sup row (16 lanes x 8B = full 128B row). 4 accs/lane;
    // shfl_xor(16)+shfl_xor(32) combine; lanes 0-15 store float4 (256B).
    const int wid  = t >> 6;
    const int lane = t & 63;
    const int qg   = lane >> 4;
    const int sl   = lane & 15;
    const int act  = *active;

    for (int r = wid; r < 128; r += 16) {
        int row = b * 128 + r;
        if (row >= N_NODES) break;   // wave-uniform (last bucket tail only)
        const int s = sc[r] - h[r];
        const int e = sc[r];
        float a0 = 0.f, a1 = 0.f, a2 = 0.f, a3 = 0.f;
        int j = s;
        for (; j + 8 <= e; j += 8) {   // 2 groups in flight (MLP)
            int2 da = stB[j + qg];
            int2 db = stB[j + 4 + qg];
            uint2 ua = *(const uint2*)(sup + ((size_t)da.x << 6) + sl * 4);
            uint2 ub = *(const uint2*)(sup + ((size_t)db.x << 6) + sl * 4);
            float wa = __int_as_float(da.y);
            float wb = __int_as_float(db.y);
            float2 va01 = __half22float2(*(const __half2*)&ua.x);
            float2 va23 = __half22float2(*(const __half2*)&ua.y);
            float2 vb01 = __half22float2(*(const __half2*)&ub.x);
            float2 vb23 = __half22float2(*(const __half2*)&ub.y);
            a0 += wa * va01.x; a1 += wa * va01.y;
            a2 += wa * va23.x; a3 += wa * va23.y;
            a0 += wb * vb01.x; a1 += wb * vb01.y;
            a2 += wb * vb23.x; a3 += wb * vb23.y;
        }
        for (; j + 4 <= e; j += 4) {
            int2 d = stB[j + qg];
            uint2 u = *(const uint2*)(sup + ((size_t)d.x << 6) + sl * 4);
            float w = __int_as_float(d.y);
            float2 v01 = __half22float2(*(const __half2*)&u.x);
            float2 v23 = __half22float2(*(const __half2*)&u.y);
            a0 += w * v01.x; a1 += w * v01.y;
            a2 += w * v23.x; a3 += w * v23.y;
        }
        if (j + qg < e) {   // tail: 1-3 edges, per-quarter predicated
            int2 d = stB[j + qg];
            uint2 u = *(const uint2*)(sup + ((size_t)d.x << 6) + sl * 4);
            float w = __int_as_float(d.y);
            float2 v01 = __half22float2(*(const __half2*)&u.x);
            float2 v23 = __half22float2(*(const __half2*)&u.y);
            a0 += w * v01.x; a1 += w * v01.y;
            a2 += w * v23.x; a3 += w * v23.y;
        }

        a0 += __shfl_xor(a0, 16, 64); a0 += __shfl_xor(a0, 32, 64);
        a1 += __shfl_xor(a1, 16, 64); a1 += __shfl_xor(a1, 32, 64);
        a2 += __shfl_xor(a2, 16, 64); a2 += __shfl_xor(a2, 32, 64);
        a3 += __shfl_xor(a3, 16, 64); a3 += __shfl_xor(a3, 32, 64);

        if (lane < 16) {
            if (act) { a0 = tanhf(a0); a1 = tanhf(a1); a2 = tanhf(a2); a3 = tanhf(a3); }
            *(float4*)&out[((size_t)row << 6) + sl * 4] = make_float4(a0, a1, a2, a3);
        }
    }
}

extern "C" void kernel_launch(void* const* d_in, const int* in_sizes, int n_in,
                              void* d_out, int out_size, void* d_ws, size_t ws_size,
                              hipStream_t stream) {
    const float* feat = (const float*)d_in[0];
    const float* W    = (const float*)d_in[1];
    const int*   erow = (const int*)d_in[2];
    const int*   ecol = (const int*)d_in[3];
    const float* ew   = (const float*)d_in[4];
    const int*   act  = (const int*)d_in[5];
    float* out = (float*)d_out;

    const int E = in_sizes[2];
    const int G = (E + CHUNK - 1) / CHUNK;

    // workspace carve-up (16B-aligned segments)
    char* ws = (char*)d_ws;
    __half* sup  = (__half*)ws; ws += (size_t)N_NODES * OUT_F * 2;     // 6.4 MB
    int2*   ecw  = (int2*)ws;   ws += (size_t)NBUCK * CAPB * 8;        // 14.4 MB
    int*    gcnt = (int*)ws;    ws += ((size_t)NBUCK * 4 + 15) & ~15;  // 1.6 KB
    short*  Whi  = (short*)ws;  ws += (size_t)OUT_F * IN_F * 2;        // 32 KB
    short*  Wlo  = (short*)ws;  ws += (size_t)OUT_F * IN_F * 2;        // 32 KB

    wprep_kernel<<<8, 256, 0, stream>>>(W, Whi, Wlo, gcnt);
    gemm_kernel<<<(N_NODES + 127) / 128, 256, 0, stream>>>(feat, Whi, Wlo, sup);
    bin_kernel<<<G, 1024, 0, stream>>>(erow, ecol, ew, gcnt, ecw, E);
    reduce_kernel<<<NBUCK, 1024, 0, stream>>>(sup, gcnt, ecw, act, out);
}